// Round 17
// baseline (511.023 us; speedup 1.0000x reference)
//
#include <hip/hip_runtime.h>
#include <hip/hip_bf16.h>

#define T_PRIOR 168
#define N_FEAT 11
#define DEC_FEAT 7
#define T_DEC 48
#define BATCH 8192
#define XROWU 136                // ushorts per staged row: 8 slots x 16 + 8-ushort zero pad (272 B)
#define ROWB (XROWU*2)           // 272 B
#define BUFB (16*ROWB)           // 4352 B per chunk buffer

typedef __attribute__((ext_vector_type(8))) short short8;
typedef __attribute__((ext_vector_type(4))) float f32x4;
typedef __attribute__((ext_vector_type(2))) float f32x2;
typedef __attribute__((ext_vector_type(4))) int i32x4;

#define MFMA __builtin_amdgcn_mfma_f32_16x16x32_bf16
#define L2E 1.4426950408889634f   // log2(e); gates run in exp2 domain (weights pre-scaled)

static __device__ __forceinline__ unsigned fbits(float f){union{float f;unsigned u;}v;v.f=f;return v.u;}
static __device__ __forceinline__ unsigned short bf16rne(float f){
    unsigned x=fbits(f);
    return (unsigned short)((x+0x7fffu+((x>>16)&1u))>>16);
}
static __device__ __forceinline__ float sigm2(float xs){
    return __builtin_amdgcn_rcpf(1.0f + __builtin_amdgcn_exp2f(-xs));
}
static __device__ __forceinline__ float tanh2(float ys){
    return fmaf(2.0f, __builtin_amdgcn_rcpf(1.0f + __builtin_amdgcn_exp2f(-ys)), -1.0f);
}
static __device__ __forceinline__ short8 s8(i32x4 v){union{i32x4 i;short8 s;}q;q.i=v;return q.s;}
static __device__ __forceinline__ unsigned pk2bf(float a, float b){
    __hip_bfloat162 p = __float22bfloat162_rn(make_float2(a, b));
    union { __hip_bfloat162 h; unsigned u; } cv; cv.h = p; return cv.u;   // low16=a, high16=b
}

__global__ __launch_bounds__(512)
void gru_ks(const float* __restrict__ prior, const float* __restrict__ teacher,
            const float* __restrict__ eWih, const float* __restrict__ eWhh,
            const float* __restrict__ eBih, const float* __restrict__ eBhh,
            const float* __restrict__ dWih, const float* __restrict__ dWhh,
            const float* __restrict__ dBih, const float* __restrict__ dBhh,
            const float* __restrict__ fcW, const float* __restrict__ fcB,
            float* __restrict__ out)
{
    __shared__ __align__(16) unsigned short sH[1024];       // 16 rows x 64 units bf16, swizzled (single buf)
    __shared__ __align__(16) float sXch[2][4][4][128];      // [sW][u][qt R,Z,H,I][lane*2] f32x2 exchange
    __shared__ __align__(16) unsigned short sX[2*16*XROWU]; // staged bf16 inputs, chunk dbuf
    __shared__ __align__(16) float sPartial[2][16][4];      // [parity][row][u]

    const int tid  = (int)threadIdx.x;
    const int lane = tid & 63;
    const int w    = tid >> 6;                               // 0..7
    const int u    = w & 3;                                  // unit tile
    const int sW   = __builtin_amdgcn_readfirstlane(w >> 2); // K-half (wave-uniform)
    const int c    = lane & 15;                              // batch row (A) / unit col (B,C)
    const int g    = lane >> 4;                              // k-group
    const int row0 = (int)blockIdx.x * 16;

    // ---- sH addresses (identity unit layout, XOR-swizzle (c&7)<<4; R15/R16-proven) ----
    const unsigned cs = ((unsigned)(c & 7)) << 4;
    const unsigned rbA = (unsigned)(c*128) + (((unsigned)(sW*64 + g*16)) ^ cs);
    unsigned pubOff[2];
#pragma unroll
    for (int q = 0; q < 2; ++q) {
        int r = g*4 + sW*2 + q;    // this wave's 2 batch rows
        pubOff[q] = (unsigned)(r*128) + (((unsigned)(32*u + 2*c)) ^ (((unsigned)(r&7))<<4));
    }

    // ---- x fragment read offsets (zeroed row-pad for out-of-range g) ----
    const unsigned xRowB = (unsigned)(c*ROWB);
    const unsigned xE_off = (g < 2) ? (unsigned)(g*16) : 256u;
    const unsigned xE_mul = (g < 2) ? 32u : 0u;
    const unsigned xD_off = (g == 0) ? 0u : 256u;
    const unsigned xD_mul = (g == 0) ? 32u : 0u;
    char* sXB = (char*)sX;

    // ---- exchange pointers ----
    float* xw = &sXch[sW][u][0][0] + lane*2;        // own write region (qt stride 128 f32)
    const float* xr = &sXch[sW^1][u][0][0] + lane*2;// partner read region

    // ---- staging setup (first 4 waves) ----
    const bool stager = (tid < 256);
    const int srow = (tid & 255) >> 4, sli = tid & 15;
    char* sXwr = sXB + srow*ROWB;
    int offE[6], offD[4];
#pragma unroll
    for (int n = 0; n < 6; ++n) { int k = sli + 16*n; offE[n] = ((k/11)*16 + (k%11))*2; }
#pragma unroll
    for (int n = 0; n < 4; ++n) { int k = sli + 16*n; offD[n] = ((k/7)*16 + (k%7))*2; }
    const float* gP = prior   + (size_t)(row0 + srow)*(T_PRIOR*N_FEAT) + sli;
    const float* gT = teacher + (size_t)(row0 + srow)*(T_DEC*DEC_FEAT) + sli;

    // ---- per-wave weights: K-half only (lean) ----
    short8 BHH[3];       // [gate], k = sW*32 + g*8 + j, identity units, exp2-scaled
    short8 BIx[2];       // sW0: [I]; sW1: [R, Z]
    float bR, bZ, bH, bI;   // scalar biases, added post-exchange
    auto loadPhase = [&](const float* Wih, const float* Whh,
                         const float* bih, const float* bhh, int kv) {
        const int rwb = u*16 + c;
#pragma unroll
        for (int gate = 0; gate < 3; ++gate) {
            const float gs = (gate == 2) ? (2.0f*L2E) : L2E;
            const int rw = gate*64 + rwb;
            union { short8 v; unsigned short s[8]; } fh;
#pragma unroll
            for (int j = 0; j < 8; ++j)
                fh.s[j] = bf16rne(Whh[rw*64 + sW*32 + g*8 + j] * gs);
            BHH[gate] = fh.v;
        }
        auto mkBI = [&](int gate) -> short8 {
            const float gs = (gate == 2) ? (2.0f*L2E) : L2E;
            const int rw = gate*64 + rwb;
            union { short8 v; unsigned short s[8]; } fi;
#pragma unroll
            for (int j = 0; j < 8; ++j) {
                int k = g*8 + j;
                fi.s[j] = (k < kv) ? bf16rne(Wih[rw*kv + k] * gs) : (unsigned short)0;
            }
            return fi.v;
        };
        if (sW == 0) { BIx[0] = mkBI(2); }
        else         { BIx[0] = mkBI(0); BIx[1] = mkBI(1); }
        const int un = u*16 + c;
        bR = (bih[un] + bhh[un]) * L2E;
        bZ = (bih[64+un] + bhh[64+un]) * L2E;
        bI = bih[128+un] * (2.0f*L2E);
        bH = bhh[128+un] * (2.0f*L2E);
    };

    const f32x4 z4 = (f32x4){0.0f, 0.0f, 0.0f, 0.0f};
    f32x4 xpR, xpZ, xpI;          // hoisted x-parts (encoder)
    f32x4 aR, aZ, aH, aI;         // phase1 -> phase2
    float h0 = 0.0f, h1 = 0.0f;
    float fwc = 0.0f, fb = 0.0f;

    auto xpartE = [&](short8 xf) {
        if (sW == 0) { xpI = MFMA(xf, BIx[0], z4, 0,0,0); }
        else         { xpR = MFMA(xf, BIx[0], z4, 0,0,0);
                       xpZ = MFMA(xf, BIx[1], z4, 0,0,0); }
    };

    auto xch_write = [&]() {
        if (sW == 0) {
            *(f32x2*)(xw +   0) = (f32x2){aR[2], aR[3]};
            *(f32x2*)(xw + 128) = (f32x2){aZ[2], aZ[3]};
            *(f32x2*)(xw + 256) = (f32x2){aH[2], aH[3]};
            *(f32x2*)(xw + 384) = (f32x2){aI[2], aI[3]};
        } else {
            *(f32x2*)(xw +   0) = (f32x2){aR[0], aR[1]};
            *(f32x2*)(xw + 128) = (f32x2){aZ[0], aZ[1]};
            *(f32x2*)(xw + 256) = (f32x2){aH[0], aH[1]};
        }
    };

    // encoder phase1: 1 ds_read + 3 MFMA (C-in = hoisted x-parts)
    auto phase1E = [&]() {
        short8 a = *(const short8*)((const char*)sH + rbA);
        __builtin_amdgcn_s_setprio(1);
        if (sW == 0) {
            aR = MFMA(a, BHH[0], z4, 0,0,0);
            aZ = MFMA(a, BHH[1], z4, 0,0,0);
            aH = MFMA(a, BHH[2], z4, 0,0,0);
            aI = xpI;
        } else {
            aR = MFMA(a, BHH[0], xpR, 0,0,0);
            aZ = MFMA(a, BHH[1], xpZ, 0,0,0);
            aH = MFMA(a, BHH[2], z4, 0,0,0);
        }
        __builtin_amdgcn_s_setprio(0);
        xch_write();
    };

    // decoder phase1: x not hoisted (pred patch), 4-5 MFMA
    auto phase1D = [&](short8 xf) {
        short8 a = *(const short8*)((const char*)sH + rbA);
        __builtin_amdgcn_s_setprio(1);
        if (sW == 0) {
            aR = MFMA(a, BHH[0], z4, 0,0,0);
            aZ = MFMA(a, BHH[1], z4, 0,0,0);
            aH = MFMA(a, BHH[2], z4, 0,0,0);
            aI = MFMA(xf, BIx[0], z4, 0,0,0);
        } else {
            aR = MFMA(a, BHH[0], z4, 0,0,0);
            aR = MFMA(xf, BIx[0], aR, 0,0,0);
            aZ = MFMA(a, BHH[1], z4, 0,0,0);
            aZ = MFMA(xf, BIx[1], aZ, 0,0,0);
            aH = MFMA(a, BHH[2], z4, 0,0,0);
        }
        __builtin_amdgcn_s_setprio(0);
        xch_write();
    };

    // phase2: combine partner partials + scalar biases, gates (2 rows), publish
    auto phase2 = [&]() {
        f32x2 pR = *(const f32x2*)(xr +   0);
        f32x2 pZ = *(const f32x2*)(xr + 128);
        f32x2 pH = *(const f32x2*)(xr + 256);
        float Rt0, Rt1, Zt0, Zt1, Ht0, Ht1, It0, It1;
        if (sW == 0) {
            Rt0 = aR[0]+pR[0]+bR; Rt1 = aR[1]+pR[1]+bR;
            Zt0 = aZ[0]+pZ[0]+bZ; Zt1 = aZ[1]+pZ[1]+bZ;
            Ht0 = aH[0]+pH[0]+bH; Ht1 = aH[1]+pH[1]+bH;
            It0 = aI[0]+bI;       It1 = aI[1]+bI;
        } else {
            f32x2 pI = *(const f32x2*)(xr + 384);
            Rt0 = aR[2]+pR[0]+bR; Rt1 = aR[3]+pR[1]+bR;
            Zt0 = aZ[2]+pZ[0]+bZ; Zt1 = aZ[3]+pZ[1]+bZ;
            Ht0 = aH[2]+pH[0]+bH; Ht1 = aH[3]+pH[1]+bH;
            It0 = pI[0]+bI;       It1 = pI[1]+bI;
        }
        float rr0 = sigm2(Rt0), zz0 = sigm2(Zt0);
        float nn0 = tanh2(fmaf(rr0, Ht0, It0));
        h0 = nn0 + zz0*(h0 - nn0);
        float rr1 = sigm2(Rt1), zz1 = sigm2(Zt1);
        float nn1 = tanh2(fmaf(rr1, Ht1, It1));
        h1 = nn1 + zz1*(h1 - nn1);
        unsigned w01 = pk2bf(h0, h1);
        *(unsigned short*)((char*)sH + pubOff[0]) = (unsigned short)(w01 & 0xffffu);
        *(unsigned short*)((char*)sH + pubOff[1]) = (unsigned short)(w01 >> 16);
    };

    // ---------------- prologue ----------------
    if (tid < 512) ((unsigned*)sH)[tid] = 0u;           // h(0) = 0
    // zero encoder pads: f=11..15 (640/buf) + row pad (128/buf), both buffers = 1536
#pragma unroll
    for (int it = 0; it < 3; ++it) {
        int e = tid + 512*it;
        int b = e / 768, rem = e % 768;
        int idx;
        if (rem < 640) {
            int r = rem / 40, q2 = rem % 40;
            idx = b*(16*XROWU) + r*XROWU + (q2/5)*16 + 11 + q2%5;
        } else {
            int rem2 = rem - 640;
            idx = b*(16*XROWU) + (rem2 >> 3)*XROWU + 128 + (rem2 & 7);
        }
        sX[idx] = 0;
    }
    loadPhase(eWih, eWhh, eBih, eBhh, N_FEAT);
    if (stager) {   // stage encoder chunk 0
        float sv[6];
#pragma unroll
        for (int n = 0; n < 5; ++n) sv[n] = gP[16*n];
        sv[5] = (sli < 8) ? gP[80] : 0.0f;
#pragma unroll
        for (int n = 0; n < 5; ++n) *(unsigned short*)(sXwr + offE[n]) = bf16rne(sv[n]);
        if (sli < 8) *(unsigned short*)(sXwr + offE[5]) = bf16rne(sv[5]);
    }
    __syncthreads();
    {   // hoisted x-part for t=0
        short8 xf0 = *(const short8*)(sXB + (xRowB + xE_off));
        xpartE(xf0);
    }

    // ---------------- encoder: 21 chunks x 8 steps, 2 barriers/step ----------------
    for (int ch = 0; ch < 21; ++ch) {
        const unsigned wbo = (unsigned)(((ch + 1) & 1) * BUFB);
        const bool st = (ch < 20);
        float sv[6];
#pragma unroll
        for (int s = 0; s < 8; ++s) {
            const int t = ch*8 + s;
            __syncthreads();                 // bar1: sH(t) visible, xch free
            if (s == 0 && st && stager) {    // issue next-chunk loads
                const float* sp = gP + 88*(ch+1);
#pragma unroll
                for (int n = 0; n < 5; ++n) sv[n] = sp[16*n];
                sv[5] = (sli < 8) ? sp[80] : 0.0f;
            }
            phase1E();
            __syncthreads();                 // bar2: xch ready, sH reads done
            phase2();
            if (s == 1 && st && stager) {    // deferred staged write (~2 steps vmcnt cover)
#pragma unroll
                for (int n = 0; n < 5; ++n) *(unsigned short*)(sXwr + wbo + offE[n]) = bf16rne(sv[n]);
                if (sli < 8) *(unsigned short*)(sXwr + wbo + offE[5]) = bf16rne(sv[5]);
            }
            if (t < T_PRIOR - 1) {           // prefetch x(t+1) + hoisted x-MFMAs
                const int tn = t + 1;
                const unsigned nbo = (unsigned)(((tn >> 3) & 1) * BUFB);
                short8 xf = *(const short8*)(sXB + (nbo + xRowB + xE_off + (unsigned)(tn & 7)*xE_mul));
                xpartE(xf);
            }
        }
    }

    // ---------------- decoder setup ----------------
    __syncthreads();   // all encoder sX reads retired before pad rewrites
    loadPhase(dWih, dWhh, dBih, dBhh, DEC_FEAT);
    fwc = fcW[u*16 + c];
    fb  = fcB[0];
    // zero decoder pads f=7..15 (1152/buf x 2 = 2304)
#pragma unroll
    for (int it = 0; it < 5; ++it) {
        int e = tid + 512*it;
        if (e < 2304) {
            int b = e / 1152, rem = e % 1152;
            int r = rem / 72, q2 = rem % 72;
            sX[b*(16*XROWU) + r*XROWU + (q2/9)*16 + 7 + q2%9] = 0;
        }
    }
    if (stager) {   // stage decoder chunk 0
        float sv[4];
#pragma unroll
        for (int n = 0; n < 3; ++n) sv[n] = gT[16*n];
        sv[3] = (sli < 8) ? gT[48] : 0.0f;
#pragma unroll
        for (int n = 0; n < 3; ++n) *(unsigned short*)(sXwr + offD[n]) = bf16rne(sv[n]);
        if (sli < 8) *(unsigned short*)(sXwr + offD[3]) = bf16rne(sv[3]);
    }

    // ---------------- decoder: 6 chunks x 8 steps ----------------
    for (int ch = 0; ch < 6; ++ch) {
        const unsigned bo  = (unsigned)((ch & 1) * BUFB);
        const unsigned wbo = (unsigned)(((ch + 1) & 1) * BUFB);
        const bool st = (ch < 5);
        float sv[4];
#pragma unroll
        for (int s = 0; s < 8; ++s) {
            const int i = ch*8 + s;
            __syncthreads();                 // bar1
            if (s == 0 && st && stager) {
                const float* sp = gT + 56*(ch+1);
#pragma unroll
                for (int n = 0; n < 3; ++n) sv[n] = sp[16*n];
                sv[3] = (sli < 8) ? sp[48] : 0.0f;
            }
            const bool hasPred = (i > 0);
            i32x4 xi = *(const i32x4*)(sXB + (bo + xRowB + xD_off + (unsigned)s*xD_mul));
            if (hasPred) {                   // pred_{i-1} from parity (s&1)^1 partials
                f32x4 pp = *(const f32x4*)&sPartial[(s & 1) ^ 1][c][0];
                float pred = pp[0] + pp[1] + pp[2] + pp[3] + fb;
                if (g == 0)                  // feature 4 = ushort #4 = word2 low half
                    xi[2] = (int)(((unsigned)xi[2] & 0xffff0000u) | (unsigned)bf16rne(pred));
                if (w == 0 && g == 0)
                    out[(size_t)(row0 + c)*T_DEC + (i - 1)] = pred;
            }
            phase1D(s8(xi));
            __syncthreads();                 // bar2
            phase2();
            // fc partials over this wave's 16 units x 2 rows
            {
                float v0 = h0 * fwc, v1 = h1 * fwc;
                v0 += __shfl_xor(v0, 1, 64); v1 += __shfl_xor(v1, 1, 64);
                v0 += __shfl_xor(v0, 2, 64); v1 += __shfl_xor(v1, 2, 64);
                v0 += __shfl_xor(v0, 4, 64); v1 += __shfl_xor(v1, 4, 64);
                v0 += __shfl_xor(v0, 8, 64); v1 += __shfl_xor(v1, 8, 64);
                if (c == 0) {
                    sPartial[s & 1][g*4 + sW*2 + 0][u] = v0;
                    sPartial[s & 1][g*4 + sW*2 + 1][u] = v1;
                }
            }
            if (s == 1 && st && stager) {    // deferred staged write
#pragma unroll
                for (int n = 0; n < 3; ++n) *(unsigned short*)(sXwr + wbo + offD[n]) = bf16rne(sv[n]);
                if (sli < 8) *(unsigned short*)(sXwr + wbo + offD[3]) = bf16rne(sv[3]);
            }
        }
    }
    __syncthreads();
    if (w == 0 && g == 0) {   // final pred (i = 47, parity 1)
        f32x4 pp = *(const f32x4*)&sPartial[1][c][0];
        float pred = pp[0] + pp[1] + pp[2] + pp[3] + fb;
        out[(size_t)(row0 + c)*T_DEC + (T_DEC - 1)] = pred;
    }
}

extern "C" void kernel_launch(void* const* d_in, const int* in_sizes, int n_in,
                              void* d_out, int out_size, void* d_ws, size_t ws_size,
                              hipStream_t stream)
{
    const float* prior   = (const float*)d_in[0];
    const float* teacher = (const float*)d_in[1];
    const float* eWih    = (const float*)d_in[2];
    const float* eWhh    = (const float*)d_in[3];
    const float* eBih    = (const float*)d_in[4];
    const float* eBhh    = (const float*)d_in[5];
    const float* dWih    = (const float*)d_in[6];
    const float* dWhh    = (const float*)d_in[7];
    const float* dBih    = (const float*)d_in[8];
    const float* dBhh    = (const float*)d_in[9];
    const float* fcW     = (const float*)d_in[10];
    const float* fcB     = (const float*)d_in[11];
    float* out = (float*)d_out;

    dim3 grid(BATCH / 16);    // 512 blocks x 8 waves = 4096 waves (4/SIMD target)
    dim3 block(512);
    hipLaunchKernelGGL(gru_ks, grid, block, 0, stream,
                       prior, teacher, eWih, eWhh, eBih, eBhh,
                       dWih, dWhh, dBih, dBhh, fcW, fcB, out);
}